// Round 12
// baseline (163.295 us; speedup 1.0000x reference)
//
#include <hip/hip_runtime.h>
#include <hip/hip_fp16.h>

// Reverb via FFT overlap-save cross-correlation. R12 = R11 (125.7us, fp16
// storage / fp32 compute, 3-pass radix-256/256/16 Stockham) with the final
// TWO kernels fused into one: inv3_norm computes the final radix-16 into
// registers, publishes block-max partials (agent-scope atomics: per-XCD L2s
// are not coherent, G16), last-arriving block reduces + releases inv_max
// via fenced flag, all blocks spin then write normalized output once from
// registers. Removes one kernel boundary AND the 21MB out r+w.
// Co-residency for the spin: 512 blocks, ~100 VGPR -> capacity >=1024.

#define L_FFT (1 << 20)
#define GSTRIDE 273
#define PSCALE (1.0f / 1048576.0f)   // 2^-20 = 1/L (fp16 range, cancels in norm)

__device__ __forceinline__ float2 h2f(__half2 h) { return __half22float2(h); }
__device__ __forceinline__ __half2 f2h(float2 v) { return __floats2half2_rn(v.x, v.y); }

__device__ __forceinline__ float2 cmul(float2 a, float2 b) {
    return make_float2(a.x * b.x - a.y * b.y, a.x * b.y + a.y * b.x);
}

__device__ __forceinline__ void rad4(float2 a, float2 b, float2 c, float2 d,
                                     float2& o0, float2& o1, float2& o2, float2& o3) {
    float2 apc = make_float2(a.x + c.x, a.y + c.y);
    float2 amc = make_float2(a.x - c.x, a.y - c.y);
    float2 bpd = make_float2(b.x + d.x, b.y + d.y);
    float2 bmd = make_float2(b.x - d.x, b.y - d.y);
    o0 = make_float2(apc.x + bpd.x, apc.y + bpd.y);
    o2 = make_float2(apc.x - bpd.x, apc.y - bpd.y);
    o1 = make_float2(amc.x + bmd.y, amc.y - bmd.x);
    o3 = make_float2(amc.x - bmd.y, amc.y + bmd.x);
}

// 16-pt DFT, natural order in/out (bench-verified R2-R11).
__device__ __forceinline__ void dft16(float2 x[16]) {
    float2 tt[16];
    rad4(x[0], x[4], x[8],  x[12], tt[0],  tt[1],  tt[2],  tt[3]);
    rad4(x[1], x[5], x[9],  x[13], tt[4],  tt[5],  tt[6],  tt[7]);
    rad4(x[2], x[6], x[10], x[14], tt[8],  tt[9],  tt[10], tt[11]);
    rad4(x[3], x[7], x[11], x[15], tt[12], tt[13], tt[14], tt[15]);
    const float C1 = 0.92387953251128675613f, S1 = 0.38268343236508977173f;
    const float C2 = 0.70710678118654752440f;
    const float2 W1 = make_float2( C1, -S1);
    const float2 W2 = make_float2( C2, -C2);
    const float2 W3 = make_float2( S1, -C1);
    const float2 W6 = make_float2(-C2, -C2);
    const float2 W9 = make_float2(-C1,  S1);
    tt[5]  = cmul(tt[5],  W1);
    tt[6]  = cmul(tt[6],  W2);
    tt[7]  = cmul(tt[7],  W3);
    tt[9]  = cmul(tt[9],  W2);
    tt[10] = make_float2(tt[10].y, -tt[10].x);
    tt[11] = cmul(tt[11], W6);
    tt[13] = cmul(tt[13], W3);
    tt[14] = cmul(tt[14], W6);
    tt[15] = cmul(tt[15], W9);
    rad4(tt[0], tt[4], tt[8],  tt[12], x[0], x[4], x[8],  x[12]);
    rad4(tt[1], tt[5], tt[9],  tt[13], x[1], x[5], x[9],  x[13]);
    rad4(tt[2], tt[6], tt[10], tt[14], x[2], x[6], x[10], x[14]);
    rad4(tt[3], tt[7], tt[11], tt[15], x[3], x[7], x[11], x[15]);
}

// 256-pt FFT across a 16-thread group (strides 273/17 === 1 mod 16:
// bank-pair = gi+row+col -> 4-way b64 floor; R5-verified).
__device__ __forceinline__ void fft256_core(float2 x[16], int i, int gi,
                                            float2* lds) {
    dft16(x);
    float sa, ca;
    __sincosf(-6.28318530717958647692f * (float)i * (1.0f / 256.0f), &sa, &ca);
    float2 w1 = make_float2(ca, sa);
    float2 w = w1;
#pragma unroll
    for (int k1 = 1; k1 < 16; ++k1) {
        x[k1] = cmul(x[k1], w);
        w = cmul(w, w1);
    }
    float2* base = lds + gi * GSTRIDE;
#pragma unroll
    for (int k1 = 0; k1 < 16; ++k1) base[i * 17 + k1] = x[k1];
    __syncthreads();
#pragma unroll
    for (int q1 = 0; q1 < 16; ++q1) x[q1] = base[q1 * 17 + i];
    dft16(x);
}

// Stage twiddle + Stockham scatter for J=256 passes.
__device__ __forceinline__ void stage256_store(float2 x[16], __half2* db,
                                               int g, int i, int J, int log2J,
                                               float invLn) {
    int j = g & (J - 1);
    int np = g >> log2J;
    float base = -6.28318530717958647692f * (float)np * invLn;
    float sa, ca;
    __sincosf(base * (float)i, &sa, &ca);
    float2 w = make_float2(ca, sa);
    __sincosf(base * 16.0f, &sa, &ca);
    float2 w16 = make_float2(ca, sa);
    size_t ob = (size_t)256 * (g - j) + j;
#pragma unroll
    for (int k2 = 0; k2 < 16; ++k2) {
        db[ob + (size_t)(i + 16 * k2) * J] = f2h(cmul(x[k2], w));
        w = cmul(w, w16);
    }
}

// J=1 store, coalesced via LDS (pad e+(e>>8): 4-way b64 floor), then
// block-contiguous window (R9-verified).
__device__ __forceinline__ void store_j1_coalesced(float2 x[16], __half2* db,
                                                   int bx, int gi, int i, int tid,
                                                   float2* lds, float invL) {
    int g = bx * 16 + gi;
    float base = -6.28318530717958647692f * (float)g * invL;
    float sa, ca;
    __sincosf(base * (float)i, &sa, &ca);
    float2 w = make_float2(ca, sa);
    __sincosf(base * 16.0f, &sa, &ca);
    float2 w16 = make_float2(ca, sa);
    __syncthreads();
#pragma unroll
    for (int k2 = 0; k2 < 16; ++k2) {
        int e = 256 * gi + i + 16 * k2;
        lds[e + (e >> 8)] = cmul(x[k2], w);
        w = cmul(w, w16);
    }
    __syncthreads();
    __half2* dwin = db + (size_t)4096 * bx;
#pragma unroll
    for (int c = 0; c < 16; ++c) {
        int e2 = tid + 256 * c;
        dwin[e2] = f2h(lds[e2 + (e2 >> 8)]);
    }
}

// ---- K1: pack + forward J=1 ----
__global__ void fwd1_pack(const float* __restrict__ audio,
                          const float* __restrict__ ir,
                          __half2* __restrict__ dst, int N, int M, int V) {
    __shared__ float2 lds[16 * GSTRIDE];
    int tid = threadIdx.x;
    int gi = tid & 15, i = tid >> 4;
    int bx = blockIdx.x, slot = blockIdx.y;
    int g = bx * 16 + gi;
    __half2* db = dst + (size_t)slot * L_FFT;

    float2 x[16];
#pragma unroll
    for (int q2 = 0; q2 < 16; ++q2) {
        int idx = g + (i + 16 * q2) * (L_FFT / 256);
        float2 v;
        if (slot == 0) {
            v = make_float2(audio[idx], audio[idx + V]);
        } else if (slot == 1) {
            float a2 = (idx + 2 * V < N) ? audio[idx + 2 * V] : 0.f;
            float a3 = (idx + 3 * V < N) ? audio[idx + 3 * V] : 0.f;
            v = make_float2(a2, a3);
        } else {
            v = make_float2((idx < M) ? ir[idx] : 0.f, 0.f);
        }
        x[q2] = v;
    }
    fft256_core(x, i, gi, lds);
    store_j1_coalesced(x, db, bx, gi, i, tid, lds, 1.0f / (float)L_FFT);
}

// ---- K4: inverse J=1 ----
__global__ void inv1(const __half2* __restrict__ src, __half2* __restrict__ dst) {
    __shared__ float2 lds[16 * GSTRIDE];
    int tid = threadIdx.x;
    int gi = tid & 15, i = tid >> 4;
    int bx = blockIdx.x;
    int g = bx * 16 + gi;
    size_t boff = (size_t)blockIdx.y * L_FFT;
    const __half2* sb = src + boff;
    __half2* db = dst + boff;
    float2 x[16];
#pragma unroll
    for (int q2 = 0; q2 < 16; ++q2)
        x[q2] = h2f(sb[g + (i + 16 * q2) * (L_FFT / 256)]);
    fft256_core(x, i, gi, lds);
    store_j1_coalesced(x, db, bx, gi, i, tid, lds, 1.0f / (float)L_FFT);
}

// ---- K2/K5: generic radix-256 pass (J=256) ----
__global__ void stage256(const __half2* __restrict__ src, __half2* __restrict__ dst,
                         int J, int log2J, float invLn) {
    __shared__ float2 lds[16 * GSTRIDE];
    int tid = threadIdx.x;
    int gi = tid & 15, i = tid >> 4;
    int g = blockIdx.x * 16 + gi;
    size_t boff = (size_t)blockIdx.y * L_FFT;
    const __half2* sb = src + boff;
    __half2* db = dst + boff;
    float2 x[16];
#pragma unroll
    for (int q2 = 0; q2 < 16; ++q2)
        x[q2] = h2f(sb[g + (i + 16 * q2) * (L_FFT / 256)]);
    fft256_core(x, i, gi, lds);
    stage256_store(x, db, g, i, J, log2J, invLn);
}

// ---- K3: fwd final radix-16 + spectral multiply ----
__global__ void fwd3_spectral(const __half2* __restrict__ A,
                              __half2* __restrict__ B) {
    __shared__ float2 XS[256 * 17];
    int tid = threadIdx.x;
    int isFwd = (tid < 128);
    int j = isFwd ? tid : (tid - 128);
    int gf = blockIdx.x * 128 + j;
    int g = isFwd ? gf : ((65536 - gf) & 65535);
    int ptid = isFwd ? (tid + 128) : (tid - 128);

    float2 h[16];
#pragma unroll
    for (int q = 0; q < 16; ++q)
        h[q] = h2f(A[(size_t)2 * L_FFT + g + (size_t)q * 65536]);
    dft16(h);
#pragma unroll
    for (int p = 0; p < 2; ++p) {
        float2 x[16];
#pragma unroll
        for (int q = 0; q < 16; ++q)
            x[q] = h2f(A[(size_t)p * L_FFT + g + (size_t)q * 65536]);
        dft16(x);
        __syncthreads();
#pragma unroll
        for (int r = 0; r < 16; ++r) XS[tid * 17 + r] = x[r];
        __syncthreads();
#pragma unroll
        for (int r = 0; r < 16; ++r) {
            int mi = (g == 0) ? ((16 - r) & 15) : (15 - r);
            float2 Z  = x[r];
            float2 Zr = XS[ptid * 17 + mi];
            float2 H  = h[r];
            float2 X0 = make_float2(0.5f * (Z.x + Zr.x), 0.5f * (Z.y - Zr.y));
            float2 X1 = make_float2(0.5f * (Z.y + Zr.y), 0.5f * (Zr.x - Z.x));
            float2 G0 = make_float2(X0.x * H.x + X0.y * H.y, X0.y * H.x - X0.x * H.y);
            float2 G1 = make_float2(X1.x * H.x + X1.y * H.y, X1.y * H.x - X1.x * H.y);
            B[(size_t)p * L_FFT + g + (size_t)r * 65536] =
                f2h(make_float2((G0.x - G1.y) * PSCALE,
                                -(G0.y + G1.x) * PSCALE));   // conj(P)/L
        }
    }
}

// ---- K6: inverse final radix-16 + max + NORMALIZED write (fused) ----
// sync[0]=arrival counter, sync[1]=release flag, sync[2]=inv_max bits.
__global__ __launch_bounds__(256) void inv3_norm(
    const __half2* __restrict__ src, float* __restrict__ out,
    float* __restrict__ partials, unsigned* __restrict__ sync, int N, int V) {
    __shared__ float sm[4];
    __shared__ int isLast;
    __shared__ float invBC;
    int tid = threadIdx.x;
    int unit = blockIdx.y * gridDim.x + blockIdx.x;   // [0, 512)
    int g = blockIdx.x * 256 + tid;
    int p = blockIdx.y;
    const __half2* sb = src + (size_t)p * L_FFT;
    float2 x[16];
#pragma unroll
    for (int q = 0; q < 16; ++q) x[q] = h2f(sb[g + q * 65536]);
    dft16(x);
    int lenO = (p == 1) ? (N - 3 * V) : V;
    float m = 0.f;
#pragma unroll
    for (int r = 0; r < 16; ++r) {
        int n = g + r * 65536;
        if (n < V)    m = fmaxf(m, fabsf(x[r].x));
        if (n < lenO) m = fmaxf(m, fabsf(x[r].y));
    }
    for (int o = 32; o > 0; o >>= 1) m = fmaxf(m, __shfl_xor(m, o));
    int lane = tid & 63, wv = tid >> 6;
    if (lane == 0) sm[wv] = m;
    __syncthreads();
    if (tid == 0) {
        float bm = fmaxf(fmaxf(sm[0], sm[1]), fmaxf(sm[2], sm[3]));
        // agent-scope store: per-XCD L2s are not coherent (G16)
        __hip_atomic_store(&partials[unit], bm, __ATOMIC_RELAXED,
                           __HIP_MEMORY_SCOPE_AGENT);
        __threadfence();
        unsigned done = atomicAdd(&sync[0], 1u);
        isLast = (done == 511u) ? 1 : 0;
    }
    __syncthreads();
    if (isLast) {
        __threadfence();   // acquire side: partials visible after counter==512
        float mm = 0.f;
        for (int i2 = tid; i2 < 512; i2 += 256)
            mm = fmaxf(mm, __hip_atomic_load(&partials[i2], __ATOMIC_RELAXED,
                                             __HIP_MEMORY_SCOPE_AGENT));
        for (int o = 32; o > 0; o >>= 1) mm = fmaxf(mm, __shfl_xor(mm, o));
        if (lane == 0) sm[wv] = mm;
        __syncthreads();
        if (tid == 0) {
            float inv = 1.0f / fmaxf(fmaxf(sm[0], sm[1]), fmaxf(sm[2], sm[3]));
            __hip_atomic_store((float*)&sync[2], inv, __ATOMIC_RELAXED,
                               __HIP_MEMORY_SCOPE_AGENT);
            __hip_atomic_store(&sync[1], 1u, __ATOMIC_RELEASE,
                               __HIP_MEMORY_SCOPE_AGENT);
        }
    }
    if (tid == 0) {
        while (__hip_atomic_load(&sync[1], __ATOMIC_ACQUIRE,
                                 __HIP_MEMORY_SCOPE_AGENT) == 0u)
            __builtin_amdgcn_s_sleep(16);
        invBC = __hip_atomic_load((float*)&sync[2], __ATOMIC_RELAXED,
                                  __HIP_MEMORY_SCOPE_AGENT);
    }
    __syncthreads();
    float inv = invBC;
    int se = 2 * p, so = 2 * p + 1;
#pragma unroll
    for (int r = 0; r < 16; ++r) {
        int n = g + r * 65536;
        if (n < V)    out[(size_t)se * V + n] = x[r].x * inv;
        if (n < lenO) out[(size_t)so * V + n] = -x[r].y * inv;
    }
}

extern "C" void kernel_launch(void* const* d_in, const int* in_sizes, int n_in,
                              void* d_out, int out_size, void* d_ws, size_t ws_size,
                              hipStream_t stream) {
    const float* audio = (const float*)d_in[0];
    const float* ir    = (const float*)d_in[1];
    float* out = (float*)d_out;

    const int N = in_sizes[0];          // 2,646,000
    const int M = in_sizes[1];          // 220,500
    const int V = L_FFT - M + 1;        // 828,077

    __half2* A = (__half2*)d_ws;                       // 3L half2
    __half2* B = A + (size_t)3 * L_FFT;                // 3L half2
    float* partials = (float*)(B + (size_t)3 * L_FFT); // 512 floats
    unsigned* syncc = (unsigned*)(partials + 512);     // 3 cells

    hipMemsetAsync(syncc, 0, 3 * sizeof(unsigned), stream);

    const float invLn2 = 1.0f / 4096.0f;

    fwd1_pack<<<dim3(256, 3), 256, 0, stream>>>(audio, ir, B, N, M, V);
    stage256<<<dim3(256, 3), 256, 0, stream>>>(B, A, 256, 8, invLn2);
    fwd3_spectral<<<257, 256, 0, stream>>>(A, B);
    inv1<<<dim3(256, 2), 256, 0, stream>>>(B, A);
    stage256<<<dim3(256, 2), 256, 0, stream>>>(A, B, 256, 8, invLn2);
    inv3_norm<<<dim3(256, 2), 256, 0, stream>>>(B, out, partials, syncc, N, V);
}

// Round 13
// 123.761 us; speedup vs baseline: 1.3194x; 1.3194x over previous
//
#include <hip/hip_runtime.h>
#include <hip/hip_fp16.h>

// Reverb via FFT overlap-save cross-correlation. R13 = R11 (125.7us champion:
// fp16 storage / fp32 compute, 3-pass radix-256/256/16 Stockham) with the
// epilogue re-shaped: inv3_max computes the final radix-16 ONLY for the max
// (no 21MB unnormalized write), norm_final re-reduces partials, recomputes
// the identical dft16 from the same fp16 input and writes normalized out
// once. Saves ~34MB vs R11's inv3_out+norm_fused. 7 slots kept: R8/R12
// proved device-side global sync (coop ~80us, spin ~40us) costs more than a
// host boundary (~12us); R6 proved pass-restructuring adds more in-kernel
// time than it saves.

#define L_FFT (1 << 20)
#define GSTRIDE 273
#define PSCALE (1.0f / 1048576.0f)   // 2^-20 = 1/L (fp16 range; cancels in norm)

__device__ __forceinline__ float2 h2f(__half2 h) { return __half22float2(h); }
__device__ __forceinline__ __half2 f2h(float2 v) { return __floats2half2_rn(v.x, v.y); }

__device__ __forceinline__ float2 cmul(float2 a, float2 b) {
    return make_float2(a.x * b.x - a.y * b.y, a.x * b.y + a.y * b.x);
}

__device__ __forceinline__ void rad4(float2 a, float2 b, float2 c, float2 d,
                                     float2& o0, float2& o1, float2& o2, float2& o3) {
    float2 apc = make_float2(a.x + c.x, a.y + c.y);
    float2 amc = make_float2(a.x - c.x, a.y - c.y);
    float2 bpd = make_float2(b.x + d.x, b.y + d.y);
    float2 bmd = make_float2(b.x - d.x, b.y - d.y);
    o0 = make_float2(apc.x + bpd.x, apc.y + bpd.y);
    o2 = make_float2(apc.x - bpd.x, apc.y - bpd.y);
    o1 = make_float2(amc.x + bmd.y, amc.y - bmd.x);
    o3 = make_float2(amc.x - bmd.y, amc.y + bmd.x);
}

// 16-pt DFT, natural order in/out (bench-verified R2-R12).
__device__ __forceinline__ void dft16(float2 x[16]) {
    float2 tt[16];
    rad4(x[0], x[4], x[8],  x[12], tt[0],  tt[1],  tt[2],  tt[3]);
    rad4(x[1], x[5], x[9],  x[13], tt[4],  tt[5],  tt[6],  tt[7]);
    rad4(x[2], x[6], x[10], x[14], tt[8],  tt[9],  tt[10], tt[11]);
    rad4(x[3], x[7], x[11], x[15], tt[12], tt[13], tt[14], tt[15]);
    const float C1 = 0.92387953251128675613f, S1 = 0.38268343236508977173f;
    const float C2 = 0.70710678118654752440f;
    const float2 W1 = make_float2( C1, -S1);
    const float2 W2 = make_float2( C2, -C2);
    const float2 W3 = make_float2( S1, -C1);
    const float2 W6 = make_float2(-C2, -C2);
    const float2 W9 = make_float2(-C1,  S1);
    tt[5]  = cmul(tt[5],  W1);
    tt[6]  = cmul(tt[6],  W2);
    tt[7]  = cmul(tt[7],  W3);
    tt[9]  = cmul(tt[9],  W2);
    tt[10] = make_float2(tt[10].y, -tt[10].x);
    tt[11] = cmul(tt[11], W6);
    tt[13] = cmul(tt[13], W3);
    tt[14] = cmul(tt[14], W6);
    tt[15] = cmul(tt[15], W9);
    rad4(tt[0], tt[4], tt[8],  tt[12], x[0], x[4], x[8],  x[12]);
    rad4(tt[1], tt[5], tt[9],  tt[13], x[1], x[5], x[9],  x[13]);
    rad4(tt[2], tt[6], tt[10], tt[14], x[2], x[6], x[10], x[14]);
    rad4(tt[3], tt[7], tt[11], tt[15], x[3], x[7], x[11], x[15]);
}

// 256-pt FFT across a 16-thread group (strides 273/17 === 1 mod 16:
// bank-pair = gi+row+col -> 4-way b64 floor; R5-verified).
__device__ __forceinline__ void fft256_core(float2 x[16], int i, int gi,
                                            float2* lds) {
    dft16(x);
    float sa, ca;
    __sincosf(-6.28318530717958647692f * (float)i * (1.0f / 256.0f), &sa, &ca);
    float2 w1 = make_float2(ca, sa);
    float2 w = w1;
#pragma unroll
    for (int k1 = 1; k1 < 16; ++k1) {
        x[k1] = cmul(x[k1], w);
        w = cmul(w, w1);
    }
    float2* base = lds + gi * GSTRIDE;
#pragma unroll
    for (int k1 = 0; k1 < 16; ++k1) base[i * 17 + k1] = x[k1];
    __syncthreads();
#pragma unroll
    for (int q1 = 0; q1 < 16; ++q1) x[q1] = base[q1 * 17 + i];
    dft16(x);
}

// Stage twiddle + Stockham scatter for J=256 passes.
__device__ __forceinline__ void stage256_store(float2 x[16], __half2* db,
                                               int g, int i, int J, int log2J,
                                               float invLn) {
    int j = g & (J - 1);
    int np = g >> log2J;
    float base = -6.28318530717958647692f * (float)np * invLn;
    float sa, ca;
    __sincosf(base * (float)i, &sa, &ca);
    float2 w = make_float2(ca, sa);
    __sincosf(base * 16.0f, &sa, &ca);
    float2 w16 = make_float2(ca, sa);
    size_t ob = (size_t)256 * (g - j) + j;
#pragma unroll
    for (int k2 = 0; k2 < 16; ++k2) {
        db[ob + (size_t)(i + 16 * k2) * J] = f2h(cmul(x[k2], w));
        w = cmul(w, w16);
    }
}

// J=1 store, coalesced via LDS (pad e+(e>>8): 4-way b64 floor), then
// block-contiguous window (R9-verified).
__device__ __forceinline__ void store_j1_coalesced(float2 x[16], __half2* db,
                                                   int bx, int gi, int i, int tid,
                                                   float2* lds, float invL) {
    int g = bx * 16 + gi;
    float base = -6.28318530717958647692f * (float)g * invL;
    float sa, ca;
    __sincosf(base * (float)i, &sa, &ca);
    float2 w = make_float2(ca, sa);
    __sincosf(base * 16.0f, &sa, &ca);
    float2 w16 = make_float2(ca, sa);
    __syncthreads();
#pragma unroll
    for (int k2 = 0; k2 < 16; ++k2) {
        int e = 256 * gi + i + 16 * k2;
        lds[e + (e >> 8)] = cmul(x[k2], w);
        w = cmul(w, w16);
    }
    __syncthreads();
    __half2* dwin = db + (size_t)4096 * bx;
#pragma unroll
    for (int c = 0; c < 16; ++c) {
        int e2 = tid + 256 * c;
        dwin[e2] = f2h(lds[e2 + (e2 >> 8)]);
    }
}

// ---- K1: pack + forward J=1 ----
__global__ void fwd1_pack(const float* __restrict__ audio,
                          const float* __restrict__ ir,
                          __half2* __restrict__ dst, int N, int M, int V) {
    __shared__ float2 lds[16 * GSTRIDE];
    int tid = threadIdx.x;
    int gi = tid & 15, i = tid >> 4;
    int bx = blockIdx.x, slot = blockIdx.y;
    int g = bx * 16 + gi;
    __half2* db = dst + (size_t)slot * L_FFT;

    float2 x[16];
#pragma unroll
    for (int q2 = 0; q2 < 16; ++q2) {
        int idx = g + (i + 16 * q2) * (L_FFT / 256);
        float2 v;
        if (slot == 0) {
            v = make_float2(audio[idx], audio[idx + V]);
        } else if (slot == 1) {
            float a2 = (idx + 2 * V < N) ? audio[idx + 2 * V] : 0.f;
            float a3 = (idx + 3 * V < N) ? audio[idx + 3 * V] : 0.f;
            v = make_float2(a2, a3);
        } else {
            v = make_float2((idx < M) ? ir[idx] : 0.f, 0.f);
        }
        x[q2] = v;
    }
    fft256_core(x, i, gi, lds);
    store_j1_coalesced(x, db, bx, gi, i, tid, lds, 1.0f / (float)L_FFT);
}

// ---- K4: inverse J=1 ----
__global__ void inv1(const __half2* __restrict__ src, __half2* __restrict__ dst) {
    __shared__ float2 lds[16 * GSTRIDE];
    int tid = threadIdx.x;
    int gi = tid & 15, i = tid >> 4;
    int bx = blockIdx.x;
    int g = bx * 16 + gi;
    size_t boff = (size_t)blockIdx.y * L_FFT;
    const __half2* sb = src + boff;
    __half2* db = dst + boff;
    float2 x[16];
#pragma unroll
    for (int q2 = 0; q2 < 16; ++q2)
        x[q2] = h2f(sb[g + (i + 16 * q2) * (L_FFT / 256)]);
    fft256_core(x, i, gi, lds);
    store_j1_coalesced(x, db, bx, gi, i, tid, lds, 1.0f / (float)L_FFT);
}

// ---- K2/K5: generic radix-256 pass (J=256) ----
__global__ void stage256(const __half2* __restrict__ src, __half2* __restrict__ dst,
                         int J, int log2J, float invLn) {
    __shared__ float2 lds[16 * GSTRIDE];
    int tid = threadIdx.x;
    int gi = tid & 15, i = tid >> 4;
    int g = blockIdx.x * 16 + gi;
    size_t boff = (size_t)blockIdx.y * L_FFT;
    const __half2* sb = src + boff;
    __half2* db = dst + boff;
    float2 x[16];
#pragma unroll
    for (int q2 = 0; q2 < 16; ++q2)
        x[q2] = h2f(sb[g + (i + 16 * q2) * (L_FFT / 256)]);
    fft256_core(x, i, gi, lds);
    stage256_store(x, db, g, i, J, log2J, invLn);
}

// ---- K3: fwd final radix-16 + spectral multiply ----
__global__ void fwd3_spectral(const __half2* __restrict__ A,
                              __half2* __restrict__ B) {
    __shared__ float2 XS[256 * 17];
    int tid = threadIdx.x;
    int isFwd = (tid < 128);
    int j = isFwd ? tid : (tid - 128);
    int gf = blockIdx.x * 128 + j;
    int g = isFwd ? gf : ((65536 - gf) & 65535);
    int ptid = isFwd ? (tid + 128) : (tid - 128);

    float2 h[16];
#pragma unroll
    for (int q = 0; q < 16; ++q)
        h[q] = h2f(A[(size_t)2 * L_FFT + g + (size_t)q * 65536]);
    dft16(h);
#pragma unroll
    for (int p = 0; p < 2; ++p) {
        float2 x[16];
#pragma unroll
        for (int q = 0; q < 16; ++q)
            x[q] = h2f(A[(size_t)p * L_FFT + g + (size_t)q * 65536]);
        dft16(x);
        __syncthreads();
#pragma unroll
        for (int r = 0; r < 16; ++r) XS[tid * 17 + r] = x[r];
        __syncthreads();
#pragma unroll
        for (int r = 0; r < 16; ++r) {
            int mi = (g == 0) ? ((16 - r) & 15) : (15 - r);
            float2 Z  = x[r];
            float2 Zr = XS[ptid * 17 + mi];
            float2 H  = h[r];
            float2 X0 = make_float2(0.5f * (Z.x + Zr.x), 0.5f * (Z.y - Zr.y));
            float2 X1 = make_float2(0.5f * (Z.y + Zr.y), 0.5f * (Zr.x - Z.x));
            float2 G0 = make_float2(X0.x * H.x + X0.y * H.y, X0.y * H.x - X0.x * H.y);
            float2 G1 = make_float2(X1.x * H.x + X1.y * H.y, X1.y * H.x - X1.x * H.y);
            B[(size_t)p * L_FFT + g + (size_t)r * 65536] =
                f2h(make_float2((G0.x - G1.y) * PSCALE,
                                -(G0.y + G1.x) * PSCALE));   // conj(P)/L
        }
    }
}

// ---- K6: inverse final radix-16, MAX ONLY (no output write) ----
__global__ void inv3_max(const __half2* __restrict__ src,
                         float* __restrict__ partials, int N, int V) {
    int g = blockIdx.x * blockDim.x + threadIdx.x;
    int p = blockIdx.y;
    const __half2* sb = src + (size_t)p * L_FFT;
    float2 x[16];
#pragma unroll
    for (int q = 0; q < 16; ++q) x[q] = h2f(sb[g + q * 65536]);
    dft16(x);
    int lenO = (p == 1) ? (N - 3 * V) : V;
    float m = 0.f;
#pragma unroll
    for (int r = 0; r < 16; ++r) {
        int n = g + r * 65536;
        if (n < V)    m = fmaxf(m, fabsf(x[r].x));
        if (n < lenO) m = fmaxf(m, fabsf(x[r].y));
    }
    for (int o = 32; o > 0; o >>= 1) m = fmaxf(m, __shfl_xor(m, o));
    __shared__ float sm[4];
    int lane = threadIdx.x & 63, wv = threadIdx.x >> 6;
    if (lane == 0) sm[wv] = m;
    __syncthreads();
    if (threadIdx.x == 0)
        partials[blockIdx.y * gridDim.x + blockIdx.x] =
            fmaxf(fmaxf(sm[0], sm[1]), fmaxf(sm[2], sm[3]));
}

// ---- K7: reduce partials, RECOMPUTE identical dft16, write normalized ----
__global__ void norm_final(const __half2* __restrict__ src,
                           float* __restrict__ out,
                           const float* __restrict__ partials, int N, int V) {
    __shared__ float sm[4];
    int tid = threadIdx.x;
    float m = 0.f;
    for (int i = tid; i < 512; i += 256) m = fmaxf(m, partials[i]);
    for (int o = 32; o > 0; o >>= 1) m = fmaxf(m, __shfl_xor(m, o));
    int lane = tid & 63, wv = tid >> 6;
    if (lane == 0) sm[wv] = m;
    __syncthreads();
    float inv = 1.0f / fmaxf(fmaxf(sm[0], sm[1]), fmaxf(sm[2], sm[3]));

    int g = blockIdx.x * blockDim.x + tid;
    int p = blockIdx.y;
    const __half2* sb = src + (size_t)p * L_FFT;
    float2 x[16];
#pragma unroll
    for (int q = 0; q < 16; ++q) x[q] = h2f(sb[g + q * 65536]);
    dft16(x);   // bit-identical to inv3_max's values (same fp16 input)
    int se = 2 * p, so = 2 * p + 1;
    int lenO = (p == 1) ? (N - 3 * V) : V;
#pragma unroll
    for (int r = 0; r < 16; ++r) {
        int n = g + r * 65536;
        if (n < V)    out[(size_t)se * V + n] = x[r].x * inv;
        if (n < lenO) out[(size_t)so * V + n] = -x[r].y * inv;
    }
}

extern "C" void kernel_launch(void* const* d_in, const int* in_sizes, int n_in,
                              void* d_out, int out_size, void* d_ws, size_t ws_size,
                              hipStream_t stream) {
    const float* audio = (const float*)d_in[0];
    const float* ir    = (const float*)d_in[1];
    float* out = (float*)d_out;

    const int N = in_sizes[0];          // 2,646,000
    const int M = in_sizes[1];          // 220,500
    const int V = L_FFT - M + 1;        // 828,077

    __half2* A = (__half2*)d_ws;                       // 3L half2
    __half2* B = A + (size_t)3 * L_FFT;                // 3L half2
    float* partials = (float*)(B + (size_t)3 * L_FFT); // 512 floats

    const float invLn2 = 1.0f / 4096.0f;

    fwd1_pack<<<dim3(256, 3), 256, 0, stream>>>(audio, ir, B, N, M, V);
    stage256<<<dim3(256, 3), 256, 0, stream>>>(B, A, 256, 8, invLn2);
    fwd3_spectral<<<257, 256, 0, stream>>>(A, B);
    inv1<<<dim3(256, 2), 256, 0, stream>>>(B, A);
    stage256<<<dim3(256, 2), 256, 0, stream>>>(A, B, 256, 8, invLn2);
    inv3_max<<<dim3(256, 2), 256, 0, stream>>>(B, partials, N, V);
    norm_final<<<dim3(256, 2), 256, 0, stream>>>(B, out, partials, N, V);
}

// Round 14
// 119.756 us; speedup vs baseline: 1.3636x; 1.0334x over previous
//
#include <hip/hip_runtime.h>
#include <hip/hip_fp16.h>

// Reverb via FFT overlap-save cross-correlation. R14 = R13 (123.8us) with:
//  (1) fwd3_spectral split over p (grid 257x2 = 514 blocks, ~2/CU instead of
//      1/CU): halves the serial chain of the worst-occupancy slot; H-dft16
//      recomputed per block (VALU is free here).
//  (2) norm_final issues its 16 strided loads BEFORE the partials reduction
//      (ILP: load latency hides under the reduce).
// Session model: bytes are L2/L3-resident (~free), ~12us/dispatch fixed cost
// dominates; coop sync (~80us), spin sync (~40us), pass restructuring (R6)
// all cost more than a host boundary. 7 slots is the proven structure.

#define L_FFT (1 << 20)
#define GSTRIDE 273
#define PSCALE (1.0f / 1048576.0f)   // 2^-20 = 1/L (fp16 range; cancels in norm)

__device__ __forceinline__ float2 h2f(__half2 h) { return __half22float2(h); }
__device__ __forceinline__ __half2 f2h(float2 v) { return __floats2half2_rn(v.x, v.y); }

__device__ __forceinline__ float2 cmul(float2 a, float2 b) {
    return make_float2(a.x * b.x - a.y * b.y, a.x * b.y + a.y * b.x);
}

__device__ __forceinline__ void rad4(float2 a, float2 b, float2 c, float2 d,
                                     float2& o0, float2& o1, float2& o2, float2& o3) {
    float2 apc = make_float2(a.x + c.x, a.y + c.y);
    float2 amc = make_float2(a.x - c.x, a.y - c.y);
    float2 bpd = make_float2(b.x + d.x, b.y + d.y);
    float2 bmd = make_float2(b.x - d.x, b.y - d.y);
    o0 = make_float2(apc.x + bpd.x, apc.y + bpd.y);
    o2 = make_float2(apc.x - bpd.x, apc.y - bpd.y);
    o1 = make_float2(amc.x + bmd.y, amc.y - bmd.x);
    o3 = make_float2(amc.x - bmd.y, amc.y + bmd.x);
}

// 16-pt DFT, natural order in/out (bench-verified R2-R13).
__device__ __forceinline__ void dft16(float2 x[16]) {
    float2 tt[16];
    rad4(x[0], x[4], x[8],  x[12], tt[0],  tt[1],  tt[2],  tt[3]);
    rad4(x[1], x[5], x[9],  x[13], tt[4],  tt[5],  tt[6],  tt[7]);
    rad4(x[2], x[6], x[10], x[14], tt[8],  tt[9],  tt[10], tt[11]);
    rad4(x[3], x[7], x[11], x[15], tt[12], tt[13], tt[14], tt[15]);
    const float C1 = 0.92387953251128675613f, S1 = 0.38268343236508977173f;
    const float C2 = 0.70710678118654752440f;
    const float2 W1 = make_float2( C1, -S1);
    const float2 W2 = make_float2( C2, -C2);
    const float2 W3 = make_float2( S1, -C1);
    const float2 W6 = make_float2(-C2, -C2);
    const float2 W9 = make_float2(-C1,  S1);
    tt[5]  = cmul(tt[5],  W1);
    tt[6]  = cmul(tt[6],  W2);
    tt[7]  = cmul(tt[7],  W3);
    tt[9]  = cmul(tt[9],  W2);
    tt[10] = make_float2(tt[10].y, -tt[10].x);
    tt[11] = cmul(tt[11], W6);
    tt[13] = cmul(tt[13], W3);
    tt[14] = cmul(tt[14], W6);
    tt[15] = cmul(tt[15], W9);
    rad4(tt[0], tt[4], tt[8],  tt[12], x[0], x[4], x[8],  x[12]);
    rad4(tt[1], tt[5], tt[9],  tt[13], x[1], x[5], x[9],  x[13]);
    rad4(tt[2], tt[6], tt[10], tt[14], x[2], x[6], x[10], x[14]);
    rad4(tt[3], tt[7], tt[11], tt[15], x[3], x[7], x[11], x[15]);
}

// 256-pt FFT across a 16-thread group (strides 273/17 === 1 mod 16:
// bank-pair = gi+row+col -> 4-way b64 floor; R5-verified).
__device__ __forceinline__ void fft256_core(float2 x[16], int i, int gi,
                                            float2* lds) {
    dft16(x);
    float sa, ca;
    __sincosf(-6.28318530717958647692f * (float)i * (1.0f / 256.0f), &sa, &ca);
    float2 w1 = make_float2(ca, sa);
    float2 w = w1;
#pragma unroll
    for (int k1 = 1; k1 < 16; ++k1) {
        x[k1] = cmul(x[k1], w);
        w = cmul(w, w1);
    }
    float2* base = lds + gi * GSTRIDE;
#pragma unroll
    for (int k1 = 0; k1 < 16; ++k1) base[i * 17 + k1] = x[k1];
    __syncthreads();
#pragma unroll
    for (int q1 = 0; q1 < 16; ++q1) x[q1] = base[q1 * 17 + i];
    dft16(x);
}

// Stage twiddle + Stockham scatter for J=256 passes.
__device__ __forceinline__ void stage256_store(float2 x[16], __half2* db,
                                               int g, int i, int J, int log2J,
                                               float invLn) {
    int j = g & (J - 1);
    int np = g >> log2J;
    float base = -6.28318530717958647692f * (float)np * invLn;
    float sa, ca;
    __sincosf(base * (float)i, &sa, &ca);
    float2 w = make_float2(ca, sa);
    __sincosf(base * 16.0f, &sa, &ca);
    float2 w16 = make_float2(ca, sa);
    size_t ob = (size_t)256 * (g - j) + j;
#pragma unroll
    for (int k2 = 0; k2 < 16; ++k2) {
        db[ob + (size_t)(i + 16 * k2) * J] = f2h(cmul(x[k2], w));
        w = cmul(w, w16);
    }
}

// J=1 store, coalesced via LDS (pad e+(e>>8): 4-way b64 floor), then
// block-contiguous window (R9-verified).
__device__ __forceinline__ void store_j1_coalesced(float2 x[16], __half2* db,
                                                   int bx, int gi, int i, int tid,
                                                   float2* lds, float invL) {
    int g = bx * 16 + gi;
    float base = -6.28318530717958647692f * (float)g * invL;
    float sa, ca;
    __sincosf(base * (float)i, &sa, &ca);
    float2 w = make_float2(ca, sa);
    __sincosf(base * 16.0f, &sa, &ca);
    float2 w16 = make_float2(ca, sa);
    __syncthreads();
#pragma unroll
    for (int k2 = 0; k2 < 16; ++k2) {
        int e = 256 * gi + i + 16 * k2;
        lds[e + (e >> 8)] = cmul(x[k2], w);
        w = cmul(w, w16);
    }
    __syncthreads();
    __half2* dwin = db + (size_t)4096 * bx;
#pragma unroll
    for (int c = 0; c < 16; ++c) {
        int e2 = tid + 256 * c;
        dwin[e2] = f2h(lds[e2 + (e2 >> 8)]);
    }
}

// ---- K1: pack + forward J=1 ----
__global__ void fwd1_pack(const float* __restrict__ audio,
                          const float* __restrict__ ir,
                          __half2* __restrict__ dst, int N, int M, int V) {
    __shared__ float2 lds[16 * GSTRIDE];
    int tid = threadIdx.x;
    int gi = tid & 15, i = tid >> 4;
    int bx = blockIdx.x, slot = blockIdx.y;
    int g = bx * 16 + gi;
    __half2* db = dst + (size_t)slot * L_FFT;

    float2 x[16];
#pragma unroll
    for (int q2 = 0; q2 < 16; ++q2) {
        int idx = g + (i + 16 * q2) * (L_FFT / 256);
        float2 v;
        if (slot == 0) {
            v = make_float2(audio[idx], audio[idx + V]);
        } else if (slot == 1) {
            float a2 = (idx + 2 * V < N) ? audio[idx + 2 * V] : 0.f;
            float a3 = (idx + 3 * V < N) ? audio[idx + 3 * V] : 0.f;
            v = make_float2(a2, a3);
        } else {
            v = make_float2((idx < M) ? ir[idx] : 0.f, 0.f);
        }
        x[q2] = v;
    }
    fft256_core(x, i, gi, lds);
    store_j1_coalesced(x, db, bx, gi, i, tid, lds, 1.0f / (float)L_FFT);
}

// ---- K4: inverse J=1 ----
__global__ void inv1(const __half2* __restrict__ src, __half2* __restrict__ dst) {
    __shared__ float2 lds[16 * GSTRIDE];
    int tid = threadIdx.x;
    int gi = tid & 15, i = tid >> 4;
    int bx = blockIdx.x;
    int g = bx * 16 + gi;
    size_t boff = (size_t)blockIdx.y * L_FFT;
    const __half2* sb = src + boff;
    __half2* db = dst + boff;
    float2 x[16];
#pragma unroll
    for (int q2 = 0; q2 < 16; ++q2)
        x[q2] = h2f(sb[g + (i + 16 * q2) * (L_FFT / 256)]);
    fft256_core(x, i, gi, lds);
    store_j1_coalesced(x, db, bx, gi, i, tid, lds, 1.0f / (float)L_FFT);
}

// ---- K2/K5: generic radix-256 pass (J=256) ----
__global__ void stage256(const __half2* __restrict__ src, __half2* __restrict__ dst,
                         int J, int log2J, float invLn) {
    __shared__ float2 lds[16 * GSTRIDE];
    int tid = threadIdx.x;
    int gi = tid & 15, i = tid >> 4;
    int g = blockIdx.x * 16 + gi;
    size_t boff = (size_t)blockIdx.y * L_FFT;
    const __half2* sb = src + boff;
    __half2* db = dst + boff;
    float2 x[16];
#pragma unroll
    for (int q2 = 0; q2 < 16; ++q2)
        x[q2] = h2f(sb[g + (i + 16 * q2) * (L_FFT / 256)]);
    fft256_core(x, i, gi, lds);
    stage256_store(x, db, g, i, J, log2J, invLn);
}

// ---- K3: fwd final radix-16 + spectral multiply, SPLIT over p ----
// blockIdx.y = p; 514 blocks (~2/CU) instead of 257 (~1/CU). H recomputed
// per block (cheap VALU). Mirror exchange unchanged within the block.
__global__ void fwd3_spectral(const __half2* __restrict__ A,
                              __half2* __restrict__ B) {
    __shared__ float2 XS[256 * 17];
    int tid = threadIdx.x;
    int p = blockIdx.y;
    int isFwd = (tid < 128);
    int j = isFwd ? tid : (tid - 128);
    int gf = blockIdx.x * 128 + j;
    int g = isFwd ? gf : ((65536 - gf) & 65535);
    int ptid = isFwd ? (tid + 128) : (tid - 128);

    float2 h[16];
#pragma unroll
    for (int q = 0; q < 16; ++q)
        h[q] = h2f(A[(size_t)2 * L_FFT + g + (size_t)q * 65536]);
    float2 x[16];
#pragma unroll
    for (int q = 0; q < 16; ++q)
        x[q] = h2f(A[(size_t)p * L_FFT + g + (size_t)q * 65536]);
    dft16(h);
    dft16(x);
#pragma unroll
    for (int r = 0; r < 16; ++r) XS[tid * 17 + r] = x[r];
    __syncthreads();
#pragma unroll
    for (int r = 0; r < 16; ++r) {
        int mi = (g == 0) ? ((16 - r) & 15) : (15 - r);
        float2 Z  = x[r];
        float2 Zr = XS[ptid * 17 + mi];
        float2 H  = h[r];
        float2 X0 = make_float2(0.5f * (Z.x + Zr.x), 0.5f * (Z.y - Zr.y));
        float2 X1 = make_float2(0.5f * (Z.y + Zr.y), 0.5f * (Zr.x - Z.x));
        float2 G0 = make_float2(X0.x * H.x + X0.y * H.y, X0.y * H.x - X0.x * H.y);
        float2 G1 = make_float2(X1.x * H.x + X1.y * H.y, X1.y * H.x - X1.x * H.y);
        B[(size_t)p * L_FFT + g + (size_t)r * 65536] =
            f2h(make_float2((G0.x - G1.y) * PSCALE,
                            -(G0.y + G1.x) * PSCALE));   // conj(P)/L
    }
}

// ---- K6: inverse final radix-16, MAX ONLY (no output write) ----
__global__ void inv3_max(const __half2* __restrict__ src,
                         float* __restrict__ partials, int N, int V) {
    int g = blockIdx.x * blockDim.x + threadIdx.x;
    int p = blockIdx.y;
    const __half2* sb = src + (size_t)p * L_FFT;
    float2 x[16];
#pragma unroll
    for (int q = 0; q < 16; ++q) x[q] = h2f(sb[g + q * 65536]);
    dft16(x);
    int lenO = (p == 1) ? (N - 3 * V) : V;
    float m = 0.f;
#pragma unroll
    for (int r = 0; r < 16; ++r) {
        int n = g + r * 65536;
        if (n < V)    m = fmaxf(m, fabsf(x[r].x));
        if (n < lenO) m = fmaxf(m, fabsf(x[r].y));
    }
    for (int o = 32; o > 0; o >>= 1) m = fmaxf(m, __shfl_xor(m, o));
    __shared__ float sm[4];
    int lane = threadIdx.x & 63, wv = threadIdx.x >> 6;
    if (lane == 0) sm[wv] = m;
    __syncthreads();
    if (threadIdx.x == 0)
        partials[blockIdx.y * gridDim.x + blockIdx.x] =
            fmaxf(fmaxf(sm[0], sm[1]), fmaxf(sm[2], sm[3]));
}

// ---- K7: reduce partials, RECOMPUTE identical dft16, write normalized ----
// Loads issued first so the partials reduction hides their latency (G7).
__global__ void norm_final(const __half2* __restrict__ src,
                           float* __restrict__ out,
                           const float* __restrict__ partials, int N, int V) {
    __shared__ float sm[4];
    int tid = threadIdx.x;
    int g = blockIdx.x * blockDim.x + tid;
    int p = blockIdx.y;
    const __half2* sb = src + (size_t)p * L_FFT;
    float2 x[16];
#pragma unroll
    for (int q = 0; q < 16; ++q) x[q] = h2f(sb[g + q * 65536]);

    float m = 0.f;
    for (int i = tid; i < 512; i += 256) m = fmaxf(m, partials[i]);
    for (int o = 32; o > 0; o >>= 1) m = fmaxf(m, __shfl_xor(m, o));
    int lane = tid & 63, wv = tid >> 6;
    if (lane == 0) sm[wv] = m;
    __syncthreads();
    float inv = 1.0f / fmaxf(fmaxf(sm[0], sm[1]), fmaxf(sm[2], sm[3]));

    dft16(x);   // bit-identical to inv3_max's values (same fp16 input)
    int se = 2 * p, so = 2 * p + 1;
    int lenO = (p == 1) ? (N - 3 * V) : V;
#pragma unroll
    for (int r = 0; r < 16; ++r) {
        int n = g + r * 65536;
        if (n < V)    out[(size_t)se * V + n] = x[r].x * inv;
        if (n < lenO) out[(size_t)so * V + n] = -x[r].y * inv;
    }
}

extern "C" void kernel_launch(void* const* d_in, const int* in_sizes, int n_in,
                              void* d_out, int out_size, void* d_ws, size_t ws_size,
                              hipStream_t stream) {
    const float* audio = (const float*)d_in[0];
    const float* ir    = (const float*)d_in[1];
    float* out = (float*)d_out;

    const int N = in_sizes[0];          // 2,646,000
    const int M = in_sizes[1];          // 220,500
    const int V = L_FFT - M + 1;        // 828,077

    __half2* A = (__half2*)d_ws;                       // 3L half2
    __half2* B = A + (size_t)3 * L_FFT;                // 3L half2
    float* partials = (float*)(B + (size_t)3 * L_FFT); // 512 floats

    const float invLn2 = 1.0f / 4096.0f;

    fwd1_pack<<<dim3(256, 3), 256, 0, stream>>>(audio, ir, B, N, M, V);
    stage256<<<dim3(256, 3), 256, 0, stream>>>(B, A, 256, 8, invLn2);
    fwd3_spectral<<<dim3(257, 2), 256, 0, stream>>>(A, B);
    inv1<<<dim3(256, 2), 256, 0, stream>>>(B, A);
    stage256<<<dim3(256, 2), 256, 0, stream>>>(A, B, 256, 8, invLn2);
    inv3_max<<<dim3(256, 2), 256, 0, stream>>>(B, partials, N, V);
    norm_final<<<dim3(256, 2), 256, 0, stream>>>(B, out, partials, N, V);
}